// Round 3
// baseline (666.775 us; speedup 1.0000x reference)
//
#include <hip/hip_runtime.h>
#include <math.h>

#define LOG2E 1.44269504088896f
#define LN2   0.69314718055995f

constexpr int SSTRIDE = 264;  // padded extended-state stride (S=257 max), 132 uint pairs

// ---------- fp16 raw-bit helpers ----------
static __device__ __forceinline__ float h2f_lo(unsigned int u) {
  unsigned short s = (unsigned short)(u & 0xffffu);
  _Float16 h; __builtin_memcpy(&h, &s, 2); return (float)h;
}
static __device__ __forceinline__ float h2f_hi(unsigned int u) {
  unsigned short s = (unsigned short)(u >> 16);
  _Float16 h; __builtin_memcpy(&h, &s, 2); return (float)h;
}
static __device__ __forceinline__ unsigned short f2h_bits(float f) {
  _Float16 h = (_Float16)f;
  unsigned short s; __builtin_memcpy(&s, &h, 2); return s;
}

// ---------- DPP cross-lane (VALU pipe, no LDS) ----------
// wave_shr1: lane i <- lane i-1; lane 0 <- old (0). gfx9 DPP ctrl 0x138.
static __device__ __forceinline__ float wave_shr1(float x) {
  int t = __builtin_amdgcn_update_dpp(0, __float_as_int(x), 0x138, 0xf, 0xf, false);
  return __int_as_float(t);
}
template <int CTRL>
static __device__ __forceinline__ float dppmax(float m) {
  int s = __float_as_int(m);
  int t = __builtin_amdgcn_update_dpp(s, s, CTRL, 0xf, 0xf, false);
  return fmaxf(m, __int_as_float(t));
}
// full-wave max -> broadcast to all lanes (values are >= 0)
static __device__ __forceinline__ float wave_max_bcast(float m) {
  m = dppmax<0x111>(m);  // row_shr:1
  m = dppmax<0x112>(m);  // row_shr:2
  m = dppmax<0x114>(m);  // row_shr:4
  m = dppmax<0x118>(m);  // row_shr:8
  m = dppmax<0x142>(m);  // row_bcast:15
  m = dppmax<0x143>(m);  // row_bcast:31  -> lane 63 has wave max
  return __int_as_float(__builtin_amdgcn_readlane(__float_as_int(m), 63));
}

// Gather v4: direct register gather, no LDS, no explicit waits.
// Wave handles 8 rows; all 24 loads/lane issued back-to-back for deep ILP.
// em[(b*T+t)*SSTRIDE + s] = fp16 exp(lp[b,t,ext[s]]), 0 where state invalid
// (linear-domain zero is absorbing -> DP needs no masking).
__global__ __launch_bounds__(256) void gather_kernel(
    const float* __restrict__ lp, const int* __restrict__ targets,
    const int* __restrict__ ilen, const int* __restrict__ tlen,
    unsigned int* __restrict__ em32, int B, int T, int C, int L, int chunks) {
  const int wave = threadIdx.x >> 6;
  const int lane = threadIdx.x & 63;
  const int b = blockIdx.x / chunks;
  const int chunk = blockIdx.x - b * chunks;
  const int t0 = chunk * 32 + wave * 8;
  const int len = ilen[b];
  int nrows = len - t0;
  if (nrows <= 0) return;
  if (nrows > 8) nrows = 8;
  const int tl = tlen[b];
  const int* tg = targets + (size_t)b * L;

  // pairs p: even state s=2p (blank), odd state s=2p+1 (label p)
  const int p0i = lane, p1i = lane + 64, p2i = lane + 128;
  const int tg0 = tg[p0i];
  const int tg1 = tg[p1i];
  const bool e0 = (p0i <= tl), o0 = (p0i < tl);
  const bool e1 = (p1i <= tl), o1 = (p1i < tl);
  const bool e2 = (p2i <= tl);             // p2i in 128..131 < 132 always

  const float* src = lp + ((size_t)b * T + t0) * C;
  float lb[8], v0[8], v1[8];
#pragma unroll
  for (int i = 0; i < 8; ++i) {            // issue phase: 24 independent loads
    const float* r = (i < nrows) ? (src + (size_t)i * C) : src;  // clamp stays in-bounds
    lb[i] = r[0];
    v0[i] = r[tg0];
    v1[i] = r[tg1];
  }
#pragma unroll
  for (int i = 0; i < 8; ++i) {            // consume phase
    if (i >= nrows) break;
    unsigned int* dst = em32 + ((size_t)b * T + t0 + i) * (SSTRIDE / 2);
    const unsigned int pbh = f2h_bits(__builtin_amdgcn_exp2f(lb[i] * LOG2E));
    const float ev0 = o0 ? __builtin_amdgcn_exp2f(v0[i] * LOG2E) : 0.f;
    const float ev1 = o1 ? __builtin_amdgcn_exp2f(v1[i] * LOG2E) : 0.f;
    dst[p0i] = (e0 ? pbh : 0u) | ((unsigned int)f2h_bits(ev0) << 16);
    dst[p1i] = (e1 ? pbh : 0u) | ((unsigned int)f2h_bits(ev1) << 16);
    if (lane < 4) dst[p2i] = (e2 ? pbh : 0u);
  }
}

// DP: linear-domain scaled forward. One wave per b, lane l owns states
// 4l..4l+3 (+ redundant 4l+4 when state 256 exists). No transcendentals and
// no LDS ops in the loop: up1 via DPP wave_shr1, rescale every 8 steps via
// 6-op DPP butterfly + readlane (zero staleness, anchor 2^108).
template <bool HAS5>
static __device__ __forceinline__ void dp_run(
    const unsigned short* base, const int* tg, int len, int tl, int l,
    float* outp) {
  // skip masks: s=4l+1 skips from alpha[4l-1] (up1); s=4l+3 skips from alpha[4l+1]
  bool sk1, sk3;
  {
    const int li1 = 2 * l;
    const int li3 = 2 * l + 1;
    sk1 = (li1 >= 1) ? (tg[li1] != tg[li1 - 1]) : false;
    sk3 = (tg[li3] != tg[li3 - 1]);
  }
  const unsigned short* lanebase = base + 4 * l;

  float a0, a1, a2, a3, a4;
  {
    uint2 v; __builtin_memcpy(&v, lanebase, 8);  // row t=0
    const float boost = 0x1.0p100f;              // initial scale 2^100 (Cexp = -100)
    a0 = (l == 0) ? h2f_lo(v.x) * boost : 0.f;
    a1 = (l == 0) ? h2f_hi(v.x) * boost : 0.f;
    a2 = 0.f; a3 = 0.f; a4 = 0.f;
  }
  int Cexp = -100;
  float up1 = 0.f;   // alpha[4l-1] from lane l-1

  constexpr int PD = 16;
  constexpr int BIAS = 108;  // rescale anchor 2^108 (alphas only decay -> no overflow)
  uint2 ring[PD];
  unsigned int ringz[PD];

  auto load = [&](int d, int idx) {
    const unsigned short* p = lanebase + (size_t)idx * SSTRIDE;
    __builtin_memcpy(&ring[d], p, 8);
    if (HAS5) ringz[d] = p[4];
  };

  auto step = [&](int d) {
    const uint2 rv = ring[d];
    const float p0 = h2f_lo(rv.x), p1 = h2f_hi(rv.x);
    const float p2 = h2f_lo(rv.y), p3 = h2f_hi(rv.y);
    const float n0 = p0 * (a0 + up1);
    const float n1 = p1 * (a1 + a0 + (sk1 ? up1 : 0.f));
    const float n2 = p2 * (a2 + a1);
    const float n3 = p3 * (a3 + a2 + (sk3 ? a1 : 0.f));
    if (HAS5) {
      const float p4 = h2f_lo(ringz[d]);
      a4 = p4 * (a4 + a3);
    }
    up1 = wave_shr1(n3);                   // VALU DPP, lane0 -> 0
    a0 = n0; a1 = n1; a2 = n2; a3 = n3;
  };

  auto rescale = [&]() {                   // zero-staleness, every 8 steps
    float m = fmaxf(fmaxf(a0, a1), fmaxf(a2, a3));
    if (HAS5) m = fmaxf(m, a4);
    const float full = wave_max_bcast(m);
    int e; (void)frexpf(full, &e);         // full==0 -> e=0, alphas stay 0
    const int sh = BIAS - e;
    a0 = ldexpf(a0, sh); a1 = ldexpf(a1, sh);
    a2 = ldexpf(a2, sh); a3 = ldexpf(a3, sh);
    if (HAS5) a4 = ldexpf(a4, sh);
    up1 = ldexpf(up1, sh);
    Cexp += e - BIAS;
  };

#pragma unroll
  for (int d = 0; d < PD; ++d) {  // prefetch rows 1..PD (clamped rows never consumed)
    int idx = 1 + d; if (idx >= len) idx = len - 1;
    load(d, idx);
  }
  int t = 1;
  for (; t + PD - 1 < len; t += PD) {
#pragma unroll
    for (int d = 0; d < PD; ++d) {
      step(d);
      if ((d & 7) == 7) rescale();
      int idx = t + d + PD; if (idx >= len) idx = len - 1;
      load(d, idx);
    }
  }
  for (int d = 0; t < len; ++t, ++d) {  // tail (<= 15 steps)
    step(d);
    if ((d & 7) == 7) rescale();
  }

  __shared__ float af[257];
  af[4 * l + 0] = a0; af[4 * l + 1] = a1;
  af[4 * l + 2] = a2; af[4 * l + 3] = a3;
  if (HAS5 && l == 63) af[256] = a4;
  __syncthreads();
  if (l == 0) {
    const int Sb = 2 * tl + 1;
    const float s = af[Sb - 1] + af[Sb - 2];
    // alpha_true = af * 2^Cexp; frexp normalizes so v_log never sees a denormal
    int e; const float m = frexpf(s, &e);
    const float llh = (__builtin_amdgcn_logf(m) + (float)(e + Cexp)) * LN2;
    *outp = -llh;
  }
}

__global__ __launch_bounds__(64) void ctc_dp_kernel(
    const unsigned short* __restrict__ em, const int* __restrict__ targets,
    const int* __restrict__ ilen, const int* __restrict__ tlen,
    float* __restrict__ out, int T, int L) {
  const int b = blockIdx.x;
  const int l = threadIdx.x;
  const int len = ilen[b];
  const int tl = tlen[b];
  const int* tg = targets + (size_t)b * L;
  const unsigned short* base = em + (size_t)b * T * SSTRIDE;
  if (tl >= L) dp_run<true>(base, tg, len, tl, l, out + b);   // state 256 live
  else         dp_run<false>(base, tg, len, tl, l, out + b);
}

extern "C" void kernel_launch(void* const* d_in, const int* in_sizes, int n_in,
                              void* d_out, int out_size, void* d_ws, size_t ws_size,
                              hipStream_t stream) {
  const float* lp = (const float*)d_in[0];
  const int* targets = (const int*)d_in[1];
  const int* ilen = (const int*)d_in[2];
  const int* tlen = (const int*)d_in[3];
  float* out = (float*)d_out;

  const int B = in_sizes[2];               // 32
  const int L = in_sizes[1] / B;           // 128
  const int C = 1024;                      // per reference
  const int T = in_sizes[0] / (B * C);     // 1600

  unsigned short* em = (unsigned short*)d_ws;  // B*T*SSTRIDE fp16 = ~27 MB
  const int chunks = (T + 31) / 32;            // 32 rows per block (4 waves x 8)

  gather_kernel<<<B * chunks, 256, 0, stream>>>(lp, targets, ilen, tlen,
                                                (unsigned int*)d_ws, B, T, C, L, chunks);
  ctc_dp_kernel<<<B, 64, 0, stream>>>(em, targets, ilen, tlen, out, T, L);
}

// Round 5
// 371.545 us; speedup vs baseline: 1.7946x; 1.7946x over previous
//
#include <hip/hip_runtime.h>
#include <math.h>

#define LOG2E 1.44269504088896f
#define LN2   0.69314718055995f

constexpr int SSTRIDE = 264;  // padded extended-state stride (S=257 max), 132 uint pairs

// ---------- fp16 raw-bit helpers ----------
static __device__ __forceinline__ float h2f_lo(unsigned int u) {
  unsigned short s = (unsigned short)(u & 0xffffu);
  _Float16 h; __builtin_memcpy(&h, &s, 2); return (float)h;
}
static __device__ __forceinline__ float h2f_hi(unsigned int u) {
  unsigned short s = (unsigned short)(u >> 16);
  _Float16 h; __builtin_memcpy(&h, &s, 2); return (float)h;
}
static __device__ __forceinline__ unsigned short f2h_bits(float f) {
  _Float16 h = (_Float16)f;
  unsigned short s; __builtin_memcpy(&s, &h, 2); return s;
}

// ---------- DPP cross-lane (VALU pipe, no LDS) ----------
// wave_shr1: lane i <- lane i-1; lane 0 <- 0. gfx9 DPP ctrl 0x138.
static __device__ __forceinline__ float wave_shr1(float x) {
  int t = __builtin_amdgcn_update_dpp(0, __float_as_int(x), 0x138, 0xf, 0xf, false);
  return __int_as_float(t);
}
template <int CTRL>
static __device__ __forceinline__ float dppmax(float m) {
  int s = __float_as_int(m);
  int t = __builtin_amdgcn_update_dpp(s, s, CTRL, 0xf, 0xf, false);
  return fmaxf(m, __int_as_float(t));
}
// full-wave max -> broadcast to all lanes (values are >= 0)
static __device__ __forceinline__ float wave_max_bcast(float m) {
  m = dppmax<0x111>(m);  // row_shr:1
  m = dppmax<0x112>(m);  // row_shr:2
  m = dppmax<0x114>(m);  // row_shr:4
  m = dppmax<0x118>(m);  // row_shr:8
  m = dppmax<0x142>(m);  // row_bcast:15
  m = dppmax<0x143>(m);  // row_bcast:31  -> lane 63 has wave max
  return __int_as_float(__builtin_amdgcn_readlane(__float_as_int(m), 63));
}

// Gather v4: direct register gather, no LDS, no explicit waits.
// Wave handles 8 rows; all 24 loads/lane issued back-to-back for deep ILP.
// em[(b*T+t)*SSTRIDE + s] = fp16 exp(lp[b,t,ext[s]]), 0 where state invalid
// (linear-domain zero is absorbing -> DP needs no masking).
__global__ __launch_bounds__(256) void gather_kernel(
    const float* __restrict__ lp, const int* __restrict__ targets,
    const int* __restrict__ ilen, const int* __restrict__ tlen,
    unsigned int* __restrict__ em32, int B, int T, int C, int L, int chunks) {
  const int wave = threadIdx.x >> 6;
  const int lane = threadIdx.x & 63;
  const int b = blockIdx.x / chunks;
  const int chunk = blockIdx.x - b * chunks;
  const int t0 = chunk * 32 + wave * 8;
  const int len = ilen[b];
  int nrows = len - t0;
  if (nrows <= 0) return;
  if (nrows > 8) nrows = 8;
  const int tl = tlen[b];
  const int* tg = targets + (size_t)b * L;

  // pairs p: even state s=2p (blank), odd state s=2p+1 (label p)
  const int p0i = lane, p1i = lane + 64, p2i = lane + 128;
  const int tg0 = tg[p0i];
  const int tg1 = tg[p1i];
  const bool e0 = (p0i <= tl), o0 = (p0i < tl);
  const bool e1 = (p1i <= tl), o1 = (p1i < tl);
  const bool e2 = (p2i <= tl);             // p2i in 128..131 < 132 always

  const float* src = lp + ((size_t)b * T + t0) * C;
  float lb[8], v0[8], v1[8];
#pragma unroll
  for (int i = 0; i < 8; ++i) {            // issue phase: 24 independent loads
    const float* r = (i < nrows) ? (src + (size_t)i * C) : src;  // clamp stays in-bounds
    lb[i] = r[0];
    v0[i] = r[tg0];
    v1[i] = r[tg1];
  }
#pragma unroll
  for (int i = 0; i < 8; ++i) {            // consume phase
    if (i >= nrows) break;
    unsigned int* dst = em32 + ((size_t)b * T + t0 + i) * (SSTRIDE / 2);
    const unsigned int pbh = f2h_bits(__builtin_amdgcn_exp2f(lb[i] * LOG2E));
    const float ev0 = o0 ? __builtin_amdgcn_exp2f(v0[i] * LOG2E) : 0.f;
    const float ev1 = o1 ? __builtin_amdgcn_exp2f(v1[i] * LOG2E) : 0.f;
    dst[p0i] = (e0 ? pbh : 0u) | ((unsigned int)f2h_bits(ev0) << 16);
    dst[p1i] = (e1 ? pbh : 0u) | ((unsigned int)f2h_bits(ev1) << 16);
    if (lane < 4) dst[p2i] = (e2 ? pbh : 0u);
  }
}

// DP: linear-domain scaled forward. One wave per b, lane l owns states
// 4l..4l+3. State 256 (even -> emission == blank == lo-half of lane0's rv.x,
// fetched via readlane) when HAS5. Prefetch ring = 16 NAMED uint2 registers,
// hand-unrolled 16-phase main loop: every access compile-time so the ring
// lives in VGPRs (R2/R3 array ring sat in scratch: VGPR_Count was 36 < ring
// size -> every step paid a serialized cache round-trip).
template <bool HAS5>
static __device__ __forceinline__ void dp_run(
    const unsigned short* base, const int* tg, int len, int tl, int l,
    float* outp) {
  // skip masks: s=4l+1 skips from alpha[4l-1] (up1); s=4l+3 skips from alpha[4l+1]
  bool sk1, sk3;
  {
    const int li1 = 2 * l;
    const int li3 = 2 * l + 1;
    sk1 = (li1 >= 1) ? (tg[li1] != tg[li1 - 1]) : false;
    sk3 = (tg[li3] != tg[li3 - 1]);
  }
  const unsigned short* lanebase = base + 4 * l;

  float a0, a1, a2, a3, a4;
  {
    uint2 v; __builtin_memcpy(&v, lanebase, 8);  // row t=0
    const float boost = 0x1.0p100f;              // initial scale 2^100 (Cexp = -100)
    a0 = (l == 0) ? h2f_lo(v.x) * boost : 0.f;
    a1 = (l == 0) ? h2f_hi(v.x) * boost : 0.f;
    a2 = 0.f; a3 = 0.f; a4 = 0.f;
  }
  int Cexp = -100;
  float up1 = 0.f;   // alpha[4l-1] from lane l-1
  constexpr int BIAS = 108;  // rescale anchor 2^108 (alphas only decay -> no overflow)

  auto loadrow = [&](int idx) -> uint2 {
    if (idx >= len) idx = len - 1;         // clamped rows are never consumed
    uint2 v; __builtin_memcpy(&v, lanebase + (size_t)idx * SSTRIDE, 8);
    return v;
  };

  auto step = [&](uint2 rv) {
    const float p0 = h2f_lo(rv.x), p1 = h2f_hi(rv.x);
    const float p2 = h2f_lo(rv.y), p3 = h2f_hi(rv.y);
    const float n0 = p0 * (a0 + up1);
    const float n1 = p1 * (a1 + a0 + (sk1 ? up1 : 0.f));
    const float n2 = p2 * (a2 + a1);
    const float n3 = p3 * (a3 + a2 + (sk3 ? a1 : 0.f));
    if (HAS5) {  // state 256 emission == blank prob == lane0's short[0]
      const float p4 = h2f_lo((unsigned int)__builtin_amdgcn_readlane((int)rv.x, 0));
      a4 = p4 * (a4 + a3);                 // old a3
    }
    up1 = wave_shr1(n3);                   // VALU DPP, lane0 -> 0
    a0 = n0; a1 = n1; a2 = n2; a3 = n3;
  };

  auto rescale = [&]() {                   // zero-staleness, every 8 steps
    float m = fmaxf(fmaxf(a0, a1), fmaxf(a2, a3));
    if (HAS5) m = fmaxf(m, a4);
    const float full = wave_max_bcast(m);
    int e; (void)frexpf(full, &e);         // full==0 -> e=0, alphas stay 0
    const int sh = BIAS - e;
    a0 = ldexpf(a0, sh); a1 = ldexpf(a1, sh);
    a2 = ldexpf(a2, sh); a3 = ldexpf(a3, sh);
    if (HAS5) a4 = ldexpf(a4, sh);
    up1 = ldexpf(up1, sh);
    Cexp += e - BIAS;
  };

  // prologue: named ring regs hold rows t..t+15 (t=1)
  uint2 r0 = loadrow(1),  r1 = loadrow(2),  r2 = loadrow(3),  r3 = loadrow(4);
  uint2 r4 = loadrow(5),  r5 = loadrow(6),  r6 = loadrow(7),  r7 = loadrow(8);
  uint2 r8 = loadrow(9),  r9 = loadrow(10), r10 = loadrow(11), r11 = loadrow(12);
  uint2 r12 = loadrow(13), r13 = loadrow(14), r14 = loadrow(15), r15 = loadrow(16);

  int t = 1;
  for (; t + 15 < len; t += 16) {
    step(r0);             r0 = loadrow(t + 16);
    step(r1);             r1 = loadrow(t + 17);
    step(r2);             r2 = loadrow(t + 18);
    step(r3);             r3 = loadrow(t + 19);
    step(r4);             r4 = loadrow(t + 20);
    step(r5);             r5 = loadrow(t + 21);
    step(r6);             r6 = loadrow(t + 22);
    step(r7); rescale();  r7 = loadrow(t + 23);
    step(r8);             r8 = loadrow(t + 24);
    step(r9);             r9 = loadrow(t + 25);
    step(r10);            r10 = loadrow(t + 26);
    step(r11);            r11 = loadrow(t + 27);
    step(r12);            r12 = loadrow(t + 28);
    step(r13);            r13 = loadrow(t + 29);
    step(r14);            r14 = loadrow(t + 30);
    step(r15); rescale(); r15 = loadrow(t + 31);
  }
  // tail: n = len - t in [0,15], static phases, uniform guards
  if (t + 0 < len)  { step(r0); }
  if (t + 1 < len)  { step(r1); }
  if (t + 2 < len)  { step(r2); }
  if (t + 3 < len)  { step(r3); }
  if (t + 4 < len)  { step(r4); }
  if (t + 5 < len)  { step(r5); }
  if (t + 6 < len)  { step(r6); }
  if (t + 7 < len)  { step(r7); rescale(); }
  if (t + 8 < len)  { step(r8); }
  if (t + 9 < len)  { step(r9); }
  if (t + 10 < len) { step(r10); }
  if (t + 11 < len) { step(r11); }
  if (t + 12 < len) { step(r12); }
  if (t + 13 < len) { step(r13); }
  if (t + 14 < len) { step(r14); }

  __shared__ float af[257];
  af[4 * l + 0] = a0; af[4 * l + 1] = a1;
  af[4 * l + 2] = a2; af[4 * l + 3] = a3;
  if (HAS5 && l == 63) af[256] = a4;
  __syncthreads();
  if (l == 0) {
    const int Sb = 2 * tl + 1;
    const float s = af[Sb - 1] + af[Sb - 2];
    // alpha_true = af * 2^Cexp; frexp normalizes so v_log never sees a denormal
    int e; const float m = frexpf(s, &e);
    const float llh = (__builtin_amdgcn_logf(m) + (float)(e + Cexp)) * LN2;
    *outp = -llh;
  }
}

__global__ __launch_bounds__(64) void ctc_dp_kernel(
    const unsigned short* __restrict__ em, const int* __restrict__ targets,
    const int* __restrict__ ilen, const int* __restrict__ tlen,
    float* __restrict__ out, int T, int L) {
  const int b = blockIdx.x;
  const int l = threadIdx.x;
  const int len = ilen[b];
  const int tl = tlen[b];
  const int* tg = targets + (size_t)b * L;
  const unsigned short* base = em + (size_t)b * T * SSTRIDE;
  if (tl >= L) dp_run<true>(base, tg, len, tl, l, out + b);   // state 256 live
  else         dp_run<false>(base, tg, len, tl, l, out + b);
}

extern "C" void kernel_launch(void* const* d_in, const int* in_sizes, int n_in,
                              void* d_out, int out_size, void* d_ws, size_t ws_size,
                              hipStream_t stream) {
  const float* lp = (const float*)d_in[0];
  const int* targets = (const int*)d_in[1];
  const int* ilen = (const int*)d_in[2];
  const int* tlen = (const int*)d_in[3];
  float* out = (float*)d_out;

  const int B = in_sizes[2];               // 32
  const int L = in_sizes[1] / B;           // 128
  const int C = 1024;                      // per reference
  const int T = in_sizes[0] / (B * C);     // 1600

  unsigned short* em = (unsigned short*)d_ws;  // B*T*SSTRIDE fp16 = ~27 MB
  const int chunks = (T + 31) / 32;            // 32 rows per block (4 waves x 8)

  gather_kernel<<<B * chunks, 256, 0, stream>>>(lp, targets, ilen, tlen,
                                                (unsigned int*)d_ws, B, T, C, L, chunks);
  ctc_dp_kernel<<<B, 64, 0, stream>>>(em, targets, ilen, tlen, out, T, L);
}